// Round 1
// baseline (5152.484 us; speedup 1.0000x reference)
//
#include <hip/hip_runtime.h>
#include <hip/hip_bf16.h>

// Problem constants
#define HH 56
#define WW 56
#define WF 29     // W/2 + 1
#define CC 768
#define BB 32
#define NB 4
#define BS 192    // block size C / NUM_BLOCKS

static constexpr float INV56  = 1.0f / 56.0f;   // ortho norm per 2D transform direction
static constexpr float TWO_PI = 6.28318530717958647692f;
static constexpr float LAMBD  = 0.01f;

// raw bf16 helpers (RNE)
__device__ __forceinline__ float bf2f(unsigned short u) {
  return __uint_as_float(((unsigned int)u) << 16);
}
__device__ __forceinline__ unsigned short f2bf(float f) {
  unsigned int u = __float_as_uint(f);
  u += 0x7fffu + ((u >> 16) & 1u);
  return (unsigned short)(u >> 16);
}

// ---------------------------------------------------------------------------
// K1: rfft along W. x (B,H,W,C) fp32 -> Y[b][kw][h][c] bf16 (r,i separate).
// grid (BB*HH, 3 c-chunks of 256), block 256.
// ---------------------------------------------------------------------------
__global__ __launch_bounds__(256) void k_rfft_w(const float* __restrict__ x,
                                                unsigned short* __restrict__ Yr,
                                                unsigned short* __restrict__ Yi) {
  __shared__ float xs[WW][256];     // 57344 B
  __shared__ float2 cst[56];
  const int t = threadIdx.x;
  if (t < 56) {
    float ang = TWO_PI * (float)t * INV56;
    cst[t] = make_float2(cosf(ang), sinf(ang));
  }
  const int bh = blockIdx.x;
  const int b = bh / HH, h = bh % HH;
  const int c0 = blockIdx.y << 8;
  const float* xp = x + ((size_t)(b * (HH * WW) + h * WW)) * CC + c0 + t;
  for (int w = 0; w < WW; ++w) xs[w][t] = xp[(size_t)w * CC];
  __syncthreads();

  const size_t obase = ((size_t)b * (WF * HH) + h) * CC + c0 + t;
  for (int kw = 0; kw < WF; ++kw) {
    float ar = 0.f, ai = 0.f;
    int ti = 0;
    for (int w = 0; w < WW; ++w) {
      float v = xs[w][t];
      float2 tw = cst[ti];
      ar = fmaf(v, tw.x, ar);
      ai = fmaf(-v, tw.y, ai);            // e^{-i theta}
      ti += kw; if (ti >= 56) ti -= 56;
    }
    size_t o = obase + (size_t)kw * (HH * CC);
    Yr[o] = f2bf(ar * INV56);
    Yi[o] = f2bf(ai * INV56);
  }
}

// ---------------------------------------------------------------------------
// K2/K4: 56-point complex DFT along H, in-place on Y.
// SIGN=-1 forward (e^{-i}), SIGN=+1 inverse (e^{+i}, no 1/N here).
// grid (BB*WF, 4 chunks of 192), block 256.
// ---------------------------------------------------------------------------
template <int SIGN>
__global__ __launch_bounds__(256) void k_fft_h(unsigned short* __restrict__ Yr,
                                               unsigned short* __restrict__ Yi) {
  __shared__ unsigned int sri[HH][BS];   // packed (r | i<<16) bf16 pairs, 43008 B
  __shared__ float2 cst[56];
  const int t = threadIdx.x;
  if (t < 56) {
    float ang = TWO_PI * (float)t * INV56;
    cst[t] = make_float2(cosf(ang), sinf(ang));
  }
  const size_t base = (size_t)blockIdx.x * (HH * CC) + blockIdx.y * BS;
  for (int j = 0; j < 42; ++j) {
    int idx = t + 256 * j;               // 56*192 = 10752 = 42*256
    int h = idx / BS, c = idx % BS;
    size_t o = base + (size_t)h * CC + c;
    sri[h][c] = (unsigned int)Yr[o] | ((unsigned int)Yi[o] << 16);
  }
  __syncthreads();
  constexpr float S = (float)SIGN;
  for (int j = 0; j < 42; ++j) {
    int idx = t + 256 * j;
    int kh = idx / BS, c = idx % BS;
    float ar = 0.f, ai = 0.f;
    int ti = 0;
    for (int h = 0; h < HH; ++h) {
      unsigned int v = sri[h][c];
      float yr = __uint_as_float(v << 16);
      float yi = __uint_as_float(v & 0xffff0000u);
      float2 w = cst[ti];
      float wr = w.x, wi = S * w.y;      // folds at compile time
      ar = fmaf(yr, wr, ar); ar = fmaf(-yi, wi, ar);
      ai = fmaf(yr, wi, ai); ai = fmaf(yi, wr, ai);
      ti += kh; if (ti >= 56) ti -= 56;
    }
    size_t o = base + (size_t)kh * CC + c;
    Yr[o] = f2bf(ar);
    Yi[o] = f2bf(ai);
  }
}

// ---------------------------------------------------------------------------
// K3: per-(b,kw,g) complex block MLP, in-place on Y.
//   h = relu(x @ (W1r + i W1i) + b1);  o = softshrink(h @ (W2r + i W2i) + b2)
// X in LDS (bf16), weight k-tiles (12x192 fp32) in LDS.
// Each thread: 2 tasks of 7 rows x 3 cols (84 fp32 accumulators).
// grid (BB*WF, NB), block 256.  LDS = 43008 + 18432 = 61440 B -> 2 blocks/CU.
// ---------------------------------------------------------------------------
__global__ __launch_bounds__(256) void k_mix(unsigned short* __restrict__ Yr,
                                             unsigned short* __restrict__ Yi,
                                             const float* __restrict__ w1,
                                             const float* __restrict__ b1,
                                             const float* __restrict__ w2,
                                             const float* __restrict__ b2) {
  __shared__ unsigned short Xr[HH][BS], Xi[HH][BS];  // 21504 B each
  __shared__ float Wr[12][BS], Wi[12][BS];           // 9216 B each
  const int t = threadIdx.x;
  const int g = blockIdx.y;
  const size_t base = (size_t)blockIdx.x * (HH * CC) + g * BS;

  // stage X (bf16 passthrough)
  for (int j = 0; j < 42; ++j) {
    int idx = t + 256 * j;
    int h = idx / BS, c = idx % BS;
    size_t o = base + (size_t)h * CC + c;
    Xr[h][c] = Yr[o];
    Xi[h][c] = Yi[o];
  }

  const int r0_0 = (t >> 6) * 7;          // rows: task0 -> rowgroups 0..3
  const int r0_1 = ((t + 256) >> 6) * 7;  //        task1 -> rowgroups 4..7
  const int cl   = (t & 63) * 3;          // cols: same for both tasks

  float aR[2][7][3], aI[2][7][3];

  auto layer = [&](const float* __restrict__ Wre, const float* __restrict__ Wim) {
#pragma unroll
    for (int s = 0; s < 2; ++s)
#pragma unroll
      for (int r = 0; r < 7; ++r)
#pragma unroll
        for (int c = 0; c < 3; ++c) { aR[s][r][c] = 0.f; aI[s][r][c] = 0.f; }

    for (int kt = 0; kt < 16; ++kt) {     // K = 192 = 16 * 12
      __syncthreads();                    // prior tile consumed / LDS writes visible
#pragma unroll
      for (int j = 0; j < 9; ++j) {       // 12*192 = 2304 = 9*256
        int idx = t + 256 * j;
        int kk = idx / BS, n = idx % BS;
        Wr[kk][n] = Wre[(kt * 12 + kk) * BS + n];
        Wi[kk][n] = Wim[(kt * 12 + kk) * BS + n];
      }
      __syncthreads();
#pragma unroll 2
      for (int kk = 0; kk < 12; ++kk) {
        const int k = kt * 12 + kk;
#pragma unroll
        for (int s = 0; s < 2; ++s) {
          const int r0 = s ? r0_1 : r0_0;
          float xr[7], xi[7], wr[3], wi[3];
#pragma unroll
          for (int r = 0; r < 7; ++r) {
            xr[r] = bf2f(Xr[r0 + r][k]);  // wave-uniform address: broadcast
            xi[r] = bf2f(Xi[r0 + r][k]);
          }
#pragma unroll
          for (int c = 0; c < 3; ++c) { wr[c] = Wr[kk][cl + c]; wi[c] = Wi[kk][cl + c]; }
#pragma unroll
          for (int r = 0; r < 7; ++r)
#pragma unroll
            for (int c = 0; c < 3; ++c) {
              aR[s][r][c] = fmaf(xr[r], wr[c], aR[s][r][c]);
              aR[s][r][c] = fmaf(-xi[r], wi[c], aR[s][r][c]);
              aI[s][r][c] = fmaf(xr[r], wi[c], aI[s][r][c]);
              aI[s][r][c] = fmaf(xi[r], wr[c], aI[s][r][c]);
            }
        }
      }
    }
  };

  // ---- layer 1 ----
  layer(w1 + (size_t)g * BS * BS, w1 + (size_t)(NB + g) * BS * BS);
  __syncthreads();  // all layer-1 reads of X done before overwriting with H
  {
    const float* b1r = b1 + g * BS;
    const float* b1i = b1 + (NB + g) * BS;
#pragma unroll
    for (int s = 0; s < 2; ++s) {
      const int r0 = s ? r0_1 : r0_0;
#pragma unroll
      for (int r = 0; r < 7; ++r)
#pragma unroll
        for (int c = 0; c < 3; ++c) {
          float hr = fmaxf(aR[s][r][c] + b1r[cl + c], 0.f);
          float hi = fmaxf(aI[s][r][c] + b1i[cl + c], 0.f);
          Xr[r0 + r][cl + c] = f2bf(hr);
          Xi[r0 + r][cl + c] = f2bf(hi);
        }
    }
  }
  // ---- layer 2 ---- (first __syncthreads inside layer() makes H visible)
  layer(w2 + (size_t)g * BS * BS, w2 + (size_t)(NB + g) * BS * BS);
  {
    const float* b2r = b2 + g * BS;
    const float* b2i = b2 + (NB + g) * BS;
#pragma unroll
    for (int s = 0; s < 2; ++s) {
      const int r0 = s ? r0_1 : r0_0;
#pragma unroll
      for (int r = 0; r < 7; ++r)
#pragma unroll
        for (int c = 0; c < 3; ++c) {
          float vr = aR[s][r][c] + b2r[cl + c];
          float vi = aI[s][r][c] + b2i[cl + c];
          float mr = fabsf(vr) - LAMBD;
          float mi = fabsf(vi) - LAMBD;
          vr = (mr > 0.f) ? copysignf(mr, vr) : 0.f;   // softshrink
          vi = (mi > 0.f) ? copysignf(mi, vi) : 0.f;
          size_t o = base + (size_t)(r0 + r) * CC + (cl + c);
          Yr[o] = f2bf(vr);
          Yi[o] = f2bf(vi);
        }
    }
  }
}

// ---------------------------------------------------------------------------
// K5: hermitian inverse rfft along W (c2r). Uses only Re of bins 0 and 28
// (pocketfft c2r semantics), weight 2 for bins 1..27. out fp32.
// grid (BB*HH, 3), block 256.
// ---------------------------------------------------------------------------
__global__ __launch_bounds__(256) void k_irfft_w(const unsigned short* __restrict__ Yr,
                                                 const unsigned short* __restrict__ Yi,
                                                 float* __restrict__ out) {
  __shared__ float sr[WF][256], si[WF][256];   // 59392 B
  __shared__ float2 cst[56];
  const int t = threadIdx.x;
  if (t < 56) {
    float ang = TWO_PI * (float)t * INV56;
    cst[t] = make_float2(cosf(ang), sinf(ang));
  }
  const int bh = blockIdx.x;
  const int b = bh / HH, h = bh % HH;
  const int c0 = blockIdx.y << 8;
  const size_t ibase = ((size_t)b * (WF * HH) + h) * CC + c0 + t;
  for (int kw = 0; kw < WF; ++kw) {
    size_t o = ibase + (size_t)kw * (HH * CC);
    float sc = (kw >= 1 && kw <= 27) ? 2.f : 1.f;
    sr[kw][t] = sc * bf2f(Yr[o]);
    si[kw][t] = sc * bf2f(Yi[o]);
  }
  __syncthreads();
  const float y0 = sr[0][t], yN = sr[28][t];
  float* op = out + ((size_t)(b * (HH * WW) + h * WW)) * CC + c0 + t;
  for (int w = 0; w < WW; ++w) {
    float acc = y0 + ((w & 1) ? -yN : yN);   // bin 28: cos = (-1)^w, sin = 0
    int ti = 0;
    for (int k = 1; k <= 27; ++k) {
      ti += w; if (ti >= 56) ti -= 56;       // ti = (k*w) mod 56
      float2 tw = cst[ti];
      acc = fmaf(sr[k][t], tw.x, acc);       // e^{+i theta}, real part
      acc = fmaf(-si[k][t], tw.y, acc);
    }
    op[(size_t)w * CC] = acc * INV56;
  }
}

// ---------------------------------------------------------------------------
extern "C" void kernel_launch(void* const* d_in, const int* in_sizes, int n_in,
                              void* d_out, int out_size, void* d_ws, size_t ws_size,
                              hipStream_t stream) {
  const float* x  = (const float*)d_in[0];
  const float* w1 = (const float*)d_in[1];
  const float* b1 = (const float*)d_in[2];
  const float* w2 = (const float*)d_in[3];
  const float* b2 = (const float*)d_in[4];
  float* out = (float*)d_out;

  // spectrum scratch: 2 * 32*29*56*768 bf16 = 159,645,696 bytes
  const size_t specN = (size_t)BB * WF * HH * CC;
  unsigned short* Yr = (unsigned short*)d_ws;
  unsigned short* Yi = Yr + specN;

  dim3 blk(256);
  k_rfft_w  <<<dim3(BB * HH, 3), blk, 0, stream>>>(x, Yr, Yi);
  k_fft_h<-1><<<dim3(BB * WF, 4), blk, 0, stream>>>(Yr, Yi);
  k_mix     <<<dim3(BB * WF, NB), blk, 0, stream>>>(Yr, Yi, w1, b1, w2, b2);
  k_fft_h<+1><<<dim3(BB * WF, 4), blk, 0, stream>>>(Yr, Yi);
  k_irfft_w <<<dim3(BB * HH, 3), blk, 0, stream>>>(Yr, Yi, out);
}